// Round 4
// baseline (134.527 us; speedup 1.0000x reference)
//
#include <hip/hip_runtime.h>
#include <hip/hip_cooperative_groups.h>
#include <math.h>

namespace cg = cooperative_groups;

#define NB 2
#define NA 128
#define KD 32
#define LS 36            // LDS row stride: 16B-aligned float4s, conflict-free
#define BN (NB*NA)       // 256 agents total
#define EPSV 1e-8f

// Cross-block scratch (only what must cross the grid sync).
__device__ __align__(16) float g_Q[BN*KD*KD];   // E^T (Sig+eps)^-1 E
__device__ __align__(16) float g_v[BN*KD];      // E^T mu
__device__ __align__(16) float g_ld[BN];        // logdet(Sig+eps)

// float offsets into the shared buffer
#define O_M   0
#define O_X   1152
#define O_X2  2304
#define O_X4  3456
#define O_B   4608      // B-poly, later ME = M*E
#define O_W   5760      // W = L^-1 E
#define O_E   6912
#define O_F   8064      // squaring ping-pong
#define O_T   9216      // T = E^T (Sig+eps) E   (never leaves LDS)
#define O_MU  10368     // 32
#define O_DG  10400     // 32 diag scratch
#define O_TOT 10432     // 41728 B
// pair-phase overlays (region 0..5023 — M/X/X2/X4/B all dead by then)
#define O_SV  0         // 4096: all v for this batch
#define O_SLD 4096      // 128
#define O_SKL 4224      // 128
#define O_SBE 4352      // 128
#define O_SP  4480      // 512
#define O_SW  4992      // 32

__device__ __forceinline__ float rdlane(float x, int l) {
  return __int_as_float(__builtin_amdgcn_readlane(__float_as_int(x), l));
}
__device__ __forceinline__ float d4(float4 a, float4 b) {
  return a.x*b.x + a.y*b.y + a.z*b.z + a.w*b.w;
}

// acc[m] += sum_q A[r0][q] * B[q][c0+m], 2 outputs (LS-strided LDS tiles)
__device__ __forceinline__ void mm2(const float* A, const float* B,
                                    int r0, int c0, float acc[2]) {
  #pragma unroll
  for (int q4 = 0; q4 < KD; q4 += 4) {
    const float4 a4 = *(const float4*)&A[r0*LS + q4];
    const float ar[4] = {a4.x, a4.y, a4.z, a4.w};
    #pragma unroll
    for (int u = 0; u < 4; ++u) {
      const float2 b2 = *(const float2*)&B[(q4+u)*LS + c0];
      acc[0] += ar[u]*b2.x; acc[1] += ar[u]*b2.y;
    }
  }
}

__global__ __launch_bounds__(512, 2) void fused_kernel(
    const float* __restrict__ mu_q, const float* __restrict__ sigma_q,
    const float* __restrict__ phi, const float* __restrict__ gen,
    float* __restrict__ out) {
  __shared__ __align__(16) float buf[O_TOT];
  const int g = blockIdx.x;
  const int b = g >> 7;
  const int i = g & (NA - 1);
  const int tid = threadIdx.x;
  const int e0 = tid * 2;
  const int r0 = e0 >> 5;
  const int c0 = e0 & 31;          // 2 consecutive cols (c0 even)

  // ================= agent phase =================
  const float p0 = phi[g*3+0], p1 = phi[g*3+1], p2 = phi[g*3+2];
  if (tid < KD) buf[O_MU + tid] = mu_q[g*KD + tid];
  {
    const float2 sg = *(const float2*)(sigma_q + (size_t)g*1024 + e0);
    const float2 g0 = *(const float2*)(gen + e0);
    const float2 g1 = *(const float2*)(gen + 1024 + e0);
    const float2 g2 = *(const float2*)(gen + 2048 + e0);
    buf[O_X + r0*LS + c0]     = p0*g0.x + p1*g1.x + p2*g2.x;
    buf[O_X + r0*LS + c0 + 1] = p0*g0.y + p1*g1.y + p2*g2.y;
    buf[O_M + r0*LS + c0]     = sg.x + ((r0 == c0)     ? EPSV : 0.f);
    buf[O_M + r0*LS + c0 + 1] = sg.y + ((r0 == c0 + 1) ? EPSV : 0.f);
  }
  __syncthreads();

  // P1: X2u = X*X (unscaled); ||X||_F^2 = -tr(X2u) since X skew
  float a2[2] = {0.f, 0.f};
  mm2(buf + O_X, buf + O_X, r0, c0, a2);
  if (c0 == r0)          buf[O_DG + r0] = a2[0];
  else if (c0 + 1 == r0) buf[O_DG + r0] = a2[1];
  __syncthreads();

  float trc = 0.f;
  #pragma unroll
  for (int r = 0; r < KD; ++r) trc += buf[O_DG + r];
  const float anorm = sqrtf(fmaxf(-trc, 0.f));
  int s = 0;
  if (anorm > 1.f) { s = (int)ceilf(log2f(anorm)); s = min(s, 15); }
  const float sc1 = exp2f((float)(-s));
  const float sc2 = sc1 * sc1;
  const float x2v0 = a2[0]*sc2, x2v1 = a2[1]*sc2;
  buf[O_X2 + r0*LS + c0]     = x2v0;
  buf[O_X2 + r0*LS + c0 + 1] = x2v1;
  __syncthreads();

  // P2: X3s = sc1*(X2*Xu), X4 = X2*X2; B = c4 I + c5 Xs + c6 X2 + c7 X3s
  const float C4 = 1.f/24.f, C5 = 1.f/120.f, C6 = 1.f/720.f, C7 = 1.f/5040.f;
  float a3[2] = {0.f,0.f}, a4[2] = {0.f,0.f};
  mm2(buf + O_X2, buf + O_X,  r0, c0, a3);
  mm2(buf + O_X2, buf + O_X2, r0, c0, a4);
  const float dlt0 = (r0 == c0) ? 1.f : 0.f, dlt1 = (r0 == c0+1) ? 1.f : 0.f;
  const float xs0 = buf[O_X + r0*LS + c0]*sc1, xs1 = buf[O_X + r0*LS + c0+1]*sc1;
  const float x3v0 = a3[0]*sc1, x3v1 = a3[1]*sc1;
  buf[O_X4 + r0*LS + c0]     = a4[0];
  buf[O_X4 + r0*LS + c0 + 1] = a4[1];
  buf[O_B + r0*LS + c0]      = C4*dlt0 + C5*xs0 + C6*x2v0 + C7*x3v0;
  buf[O_B + r0*LS + c0 + 1]  = C4*dlt1 + C5*xs1 + C6*x2v1 + C7*x3v1;
  __syncthreads();

  // P3: E = (I + Xs + X2/2 + X3s/6) + B*X4
  {
    float u[2] = {0.f, 0.f};
    mm2(buf + O_B, buf + O_X4, r0, c0, u);
    buf[O_E + r0*LS + c0]     = dlt0 + xs0 + 0.5f*x2v0 + (1.f/6.f)*x3v0 + u[0];
    buf[O_E + r0*LS + c0 + 1] = dlt1 + xs1 + 0.5f*x2v1 + (1.f/6.f)*x3v1 + u[1];
  }
  __syncthreads();

  // squarings: E <- E*E, s times
  float* pe = buf + O_E;
  float* po = buf + O_F;
  for (int t = 0; t < s; ++t) {
    float ac[2] = {0.f, 0.f};
    mm2(pe, pe, r0, c0, ac);
    po[r0*LS + c0]     = ac[0];
    po[r0*LS + c0 + 1] = ac[1];
    __syncthreads();
    float* tp = pe; pe = po; po = tp;
  }

  // chol+subst (wave0) || v = E^T mu (tids 64..95) || ME = M*E (waves 4-7)
  if (tid < 64) {
    const int ci = tid & 31;
    float acc[KD];
    #pragma unroll
    for (int r = 0; r < KD; ++r) acc[r] = pe[r*LS + ci];   // E column ci
    float row[KD];
    #pragma unroll
    for (int q4 = 0; q4 < KD; q4 += 4) {
      const float4 m4 = *(const float4*)&buf[O_M + ci*LS + q4];
      row[q4] = m4.x; row[q4+1] = m4.y; row[q4+2] = m4.z; row[q4+3] = m4.w;
    }
    float Lr[KD], dinv[KD];
    float dprod = 1.f;
    #pragma unroll
    for (int j = 0; j < KD; ++j) {
      const float djj = rdlane(row[j], j);
      const float d = sqrtf(djj);
      const float rin = 1.f / d;
      dprod *= d;
      dinv[j] = rin;
      const float lij = row[j] * rin;       // valid for lanes ci >= j
      Lr[j] = lij;
      #pragma unroll
      for (int q = j + 1; q < KD; ++q)
        row[q] = fmaf(-lij, rdlane(lij, q), row[q]);
    }
    if (tid == 0) g_ld[g] = 2.f * logf(dprod);
    #pragma unroll
    for (int q = 0; q < KD; ++q) {          // W[:,ci] = L^-1 E[:,ci]
      const float wq = acc[q] * dinv[q];
      acc[q] = wq;
      #pragma unroll
      for (int r = q + 1; r < KD; ++r)
        acc[r] = fmaf(-rdlane(Lr[q], r), wq, acc[r]);
    }
    #pragma unroll
    for (int r = 0; r < KD; ++r) buf[O_W + r*LS + ci] = acc[r];
  } else if (tid < 96) {
    const int c = tid - 64;
    float va = 0.f;
    #pragma unroll
    for (int r = 0; r < KD; ++r) va += pe[r*LS + c] * buf[O_MU + r];
    g_v[g*KD + c] = va;
  } else if (tid >= 256) {
    const int t8 = (tid - 256) * 4;         // ME = M*E -> O_B
    const int rm = t8 >> 5, cm = t8 & 31;
    float a[4] = {0.f,0.f,0.f,0.f};
    #pragma unroll
    for (int q4 = 0; q4 < KD; q4 += 4) {
      const float4 a4 = *(const float4*)&buf[O_M + rm*LS + q4];
      const float ar[4] = {a4.x, a4.y, a4.z, a4.w};
      #pragma unroll
      for (int u = 0; u < 4; ++u) {
        const float4 b4 = *(const float4*)&pe[(q4+u)*LS + cm];
        a[0] += ar[u]*b4.x; a[1] += ar[u]*b4.y;
        a[2] += ar[u]*b4.z; a[3] += ar[u]*b4.w;
      }
    }
    #pragma unroll
    for (int m = 0; m < 4; ++m) buf[O_B + rm*LS + cm + m] = a[m];
  }
  __syncthreads();

  // Q = W^T W -> global ; T = E^T (ME) -> LDS (stays local)
  {
    float aq[2] = {0.f,0.f}, at[2] = {0.f,0.f};
    #pragma unroll
    for (int q = 0; q < KD; ++q) {
      const float wq = buf[O_W + q*LS + r0];
      const float eq = pe[q*LS + r0];
      const float2 wb = *(const float2*)&buf[O_W + q*LS + c0];
      const float2 mb = *(const float2*)&buf[O_B + q*LS + c0];
      aq[0] += wq*wb.x; aq[1] += wq*wb.y;
      at[0] += eq*mb.x; at[1] += eq*mb.y;
    }
    *(float2*)&g_Q[(size_t)g*1024 + r0*KD + c0] = make_float2(aq[0], aq[1]);
    buf[O_T + r0*LS + c0]     = at[0];
    buf[O_T + r0*LS + c0 + 1] = at[1];
  }

  cg::this_grid().sync();

  // ================= pair phase =================
  {
    const float4* vs = (const float4*)(g_v + (size_t)b*NA*KD);
    float4* dv = (float4*)(buf + O_SV);
    dv[tid]       = vs[tid];
    dv[tid + 512] = vs[tid + 512];
    if (tid < NA) buf[O_SLD + tid] = g_ld[b*NA + tid];
  }

  const int lane = tid & 63;
  const int wave = tid >> 6;
  const int k  = lane >> 1;
  const int l0 = (lane & 1) * 16;

  // T_i row chunk from LDS (lane-constant over the whole j loop)
  float4 t0, t1, t2, t3;
  {
    const float* Tp = buf + O_T + k*LS + l0;
    t0 = *(const float4*)(Tp);     t1 = *(const float4*)(Tp + 4);
    t2 = *(const float4*)(Tp + 8); t3 = *(const float4*)(Tp + 12);
  }
  __syncthreads();

  float4 vi0, vi1, vi2, vi3;
  {
    const float* vp = buf + O_SV + i*KD + l0;
    vi0 = *(const float4*)(vp);     vi1 = *(const float4*)(vp + 4);
    vi2 = *(const float4*)(vp + 8); vi3 = *(const float4*)(vp + 12);
  }
  const float vik = buf[O_SV + i*KD + k];
  const float ldi = buf[O_SLD + i];
  const float* Qb = g_Q + (size_t)b*NA*1024 + k*KD + l0;

  #pragma unroll 2
  for (int j = wave; j < NA; j += 8) {
    const float4* Qp = (const float4*)(Qb + (size_t)j*1024);
    const float4 q0 = Qp[0], q1 = Qp[1], q2 = Qp[2], q3 = Qp[3];
    const float* vj = buf + O_SV + j*KD + l0;
    const float4 w0 = *(const float4*)(vj);     const float4 w1 = *(const float4*)(vj + 4);
    const float4 w2 = *(const float4*)(vj + 8); const float4 w3 = *(const float4*)(vj + 12);
    const float dk = buf[O_SV + j*KD + k] - vik;
    const float4 e0v = make_float4(w0.x-vi0.x, w0.y-vi0.y, w0.z-vi0.z, w0.w-vi0.w);
    const float4 e1v = make_float4(w1.x-vi1.x, w1.y-vi1.y, w1.z-vi1.z, w1.w-vi1.w);
    const float4 e2v = make_float4(w2.x-vi2.x, w2.y-vi2.y, w2.z-vi2.z, w2.w-vi2.w);
    const float4 e3v = make_float4(w3.x-vi3.x, w3.y-vi3.y, w3.z-vi3.z, w3.w-vi3.w);
    float sacc = d4(q0,t0) + d4(q1,t1) + d4(q2,t2) + d4(q3,t3)
               + (d4(q0,e0v) + d4(q1,e1v) + d4(q2,e2v) + d4(q3,e3v)) * dk;
    #pragma unroll
    for (int o = 1; o < 64; o <<= 1) sacc += __shfl_xor(sacc, o);
    if (lane == 0)
      buf[O_SKL + j] = fmaxf(0.5f*(sacc - (float)KD + buf[O_SLD + j] - ldi), 0.f);
  }
  __syncthreads();

  // softmax over j in one wave
  if (tid < 64) {
    const float a = buf[O_SKL + tid], c = buf[O_SKL + tid + 64];
    float mn = fminf(a, c);
    #pragma unroll
    for (int o = 1; o < 64; o <<= 1) mn = fminf(mn, __shfl_xor(mn, o));
    const float ea = expf(mn - a);
    const float eb = expf(mn - c);
    float sm = ea + eb;
    #pragma unroll
    for (int o = 1; o < 64; o <<= 1) sm += __shfl_xor(sm, o);
    const float inv = 1.f / sm;
    const float ren = 1.0f / (1.0f + 128.0f * 1e-8f);
    buf[O_SBE + tid]      = (ea*inv + 1e-8f) * ren;
    buf[O_SBE + tid + 64] = (eb*inv + 1e-8f) * ren;
  }
  __syncthreads();

  // w = sum_j beta_j v_j (16 chunks x 32 components)
  {
    const int c = tid >> 5, kk = tid & 31;
    float acc = 0.f;
    #pragma unroll
    for (int jj = 0; jj < 8; ++jj) {
      const int j = c*8 + jj;
      acc += buf[O_SBE + j] * buf[O_SV + j*KD + kk];
    }
    buf[O_SP + c*KD + kk] = acc;
  }
  __syncthreads();
  if (tid < KD) {
    float w = 0.f;
    #pragma unroll
    for (int c2 = 0; c2 < 16; ++c2) w += buf[O_SP + c2*KD + tid];
    buf[O_SW + tid] = w;
  }
  __syncthreads();
  if (tid < KD) {
    float acc = 0.f;
    #pragma unroll
    for (int l = 0; l < KD; ++l) acc += pe[tid*LS + l] * buf[O_SW + l];
    out[g*KD + tid] = acc;
  }
}

extern "C" void kernel_launch(void* const* d_in, const int* in_sizes, int n_in,
                              void* d_out, int out_size, void* d_ws, size_t ws_size,
                              hipStream_t stream) {
  (void)in_sizes; (void)n_in; (void)out_size; (void)d_ws; (void)ws_size;
  const float* mu_q    = (const float*)d_in[0];
  const float* sigma_q = (const float*)d_in[1];
  const float* phi     = (const float*)d_in[2];
  const float* gen     = (const float*)d_in[3];
  float* out = (float*)d_out;
  void* args[5] = { (void*)&mu_q, (void*)&sigma_q, (void*)&phi, (void*)&gen, (void*)&out };
  hipLaunchCooperativeKernel((void*)fused_kernel, dim3(BN), dim3(512), args, 0, stream);
}

// Round 6
// 91.453 us; speedup vs baseline: 1.4710x; 1.4710x over previous
//
#include <hip/hip_runtime.h>
#include <math.h>

#define NB 2
#define NA 128
#define KD 32
#define LS 36            // LDS row stride: conflict-free for row/col float4 access
#define BN (NB*NA)       // 256 agents total
#define EPSV 1e-8f

// Inter-kernel scratch (graph-capture-safe; fully rewritten every launch).
__device__ __align__(16) float g_Q[BN*KD*KD];   // E^T (Sig+eps)^-1 E
__device__ __align__(16) float g_T[BN*KD*KD];   // T' = E^T (Sig+eps) E + v v^T
__device__ __align__(16) float g_E[BN*KD*KD];   // expm(X)
__device__ __align__(16) float g_v[BN*KD];      // v = E^T mu
__device__ __align__(16) float g_u[BN*KD];      // u = Q v
__device__ __align__(16) float g_ld[BN];        // logdet(Sig+eps)
__device__ __align__(16) float g_c[BN];         // 0.5*(v^T Q v + ld - K)

// agent-phase LDS float offsets
#define O_M   0
#define O_X   1152
#define O_X2  2304
#define O_X4  3456
#define O_B   4608      // B-poly, later ME = M*E
#define O_W   5760      // W = L^-1 E
#define O_E   6912
#define O_F   8064      // squaring ping-pong
#define O_VV  9216      // 32: v
#define O_DG  9248      // 32: diag scratch
#define O_P   9280      // 512: u partial sums [32 rows][16]
#define O_MU  9792      // 32
#define O_LD  9824      // 1
#define O_TOT 9828      // ~39.3 KB

__device__ __forceinline__ float rdlane(float x, int l) {
  return __int_as_float(__builtin_amdgcn_readlane(__float_as_int(x), l));
}
__device__ __forceinline__ float d4(float4 a, float4 b) {
  return a.x*b.x + a.y*b.y + a.z*b.z + a.w*b.w;
}

// acc[m] += sum_q A[r0][q] * B[q][c0+m], 2 outputs (LS-strided LDS tiles)
__device__ __forceinline__ void mm2(const float* A, const float* B,
                                    int r0, int c0, float acc[2]) {
  #pragma unroll
  for (int q4 = 0; q4 < KD; q4 += 4) {
    const float4 a4 = *(const float4*)&A[r0*LS + q4];
    const float ar[4] = {a4.x, a4.y, a4.z, a4.w};
    #pragma unroll
    for (int u = 0; u < 4; ++u) {
      const float2 b2 = *(const float2*)&B[(q4+u)*LS + c0];
      acc[0] += ar[u]*b2.x; acc[1] += ar[u]*b2.y;
    }
  }
}

// ---------------- Kernel 1: per-agent factorizations ----------------
__global__ __launch_bounds__(512, 1) void agent_kernel(
    const float* __restrict__ mu_q, const float* __restrict__ sigma_q,
    const float* __restrict__ phi, const float* __restrict__ gen) {
  __shared__ __align__(16) float buf[O_TOT];
  const int g = blockIdx.x;
  const int tid = threadIdx.x;
  const int e0 = tid * 2;
  const int r0 = e0 >> 5;
  const int c0 = e0 & 31;          // 2 consecutive cols (c0 even)

  const float p0 = phi[g*3+0], p1 = phi[g*3+1], p2 = phi[g*3+2];
  if (tid < KD) buf[O_MU + tid] = mu_q[g*KD + tid];
  {
    const float2 sg = *(const float2*)(sigma_q + (size_t)g*1024 + e0);
    const float2 g0 = *(const float2*)(gen + e0);
    const float2 g1 = *(const float2*)(gen + 1024 + e0);
    const float2 g2 = *(const float2*)(gen + 2048 + e0);
    buf[O_X + r0*LS + c0]     = p0*g0.x + p1*g1.x + p2*g2.x;
    buf[O_X + r0*LS + c0 + 1] = p0*g0.y + p1*g1.y + p2*g2.y;
    buf[O_M + r0*LS + c0]     = sg.x + ((r0 == c0)     ? EPSV : 0.f);
    buf[O_M + r0*LS + c0 + 1] = sg.y + ((r0 == c0 + 1) ? EPSV : 0.f);
  }
  __syncthreads();

  // P1: X2u = X*X (unscaled); ||X||_F^2 = -tr(X2u) since X skew
  float a2[2] = {0.f, 0.f};
  mm2(buf + O_X, buf + O_X, r0, c0, a2);
  if (c0 == r0)          buf[O_DG + r0] = a2[0];
  else if (c0 + 1 == r0) buf[O_DG + r0] = a2[1];
  __syncthreads();

  float trc = 0.f;
  #pragma unroll
  for (int r = 0; r < KD; ++r) trc += buf[O_DG + r];
  const float anorm = sqrtf(fmaxf(-trc, 0.f));
  int s = 0;
  if (anorm > 1.f) { s = (int)ceilf(log2f(anorm)); s = min(s, 15); }
  const float sc1 = exp2f((float)(-s));
  const float sc2 = sc1 * sc1;
  const float x2v0 = a2[0]*sc2, x2v1 = a2[1]*sc2;
  buf[O_X2 + r0*LS + c0]     = x2v0;
  buf[O_X2 + r0*LS + c0 + 1] = x2v1;
  __syncthreads();

  // P2: X3s = sc1*(X2*Xu), X4 = X2*X2; B = c4 I + c5 Xs + c6 X2 + c7 X3s
  const float C4 = 1.f/24.f, C5 = 1.f/120.f, C6 = 1.f/720.f, C7 = 1.f/5040.f;
  float a3[2] = {0.f,0.f}, a4[2] = {0.f,0.f};
  mm2(buf + O_X2, buf + O_X,  r0, c0, a3);
  mm2(buf + O_X2, buf + O_X2, r0, c0, a4);
  const float dlt0 = (r0 == c0) ? 1.f : 0.f, dlt1 = (r0 == c0+1) ? 1.f : 0.f;
  const float xs0 = buf[O_X + r0*LS + c0]*sc1, xs1 = buf[O_X + r0*LS + c0+1]*sc1;
  const float x3v0 = a3[0]*sc1, x3v1 = a3[1]*sc1;
  buf[O_X4 + r0*LS + c0]     = a4[0];
  buf[O_X4 + r0*LS + c0 + 1] = a4[1];
  buf[O_B + r0*LS + c0]      = C4*dlt0 + C5*xs0 + C6*x2v0 + C7*x3v0;
  buf[O_B + r0*LS + c0 + 1]  = C4*dlt1 + C5*xs1 + C6*x2v1 + C7*x3v1;
  __syncthreads();

  // P3: E = (I + Xs + X2/2 + X3s/6) + B*X4
  {
    float u[2] = {0.f, 0.f};
    mm2(buf + O_B, buf + O_X4, r0, c0, u);
    buf[O_E + r0*LS + c0]     = dlt0 + xs0 + 0.5f*x2v0 + (1.f/6.f)*x3v0 + u[0];
    buf[O_E + r0*LS + c0 + 1] = dlt1 + xs1 + 0.5f*x2v1 + (1.f/6.f)*x3v1 + u[1];
  }
  __syncthreads();

  // squarings: E <- E*E, s times
  float* pe = buf + O_E;
  float* po = buf + O_F;
  for (int t = 0; t < s; ++t) {
    float ac[2] = {0.f, 0.f};
    mm2(pe, pe, r0, c0, ac);
    po[r0*LS + c0]     = ac[0];
    po[r0*LS + c0 + 1] = ac[1];
    __syncthreads();
    float* tp = pe; pe = po; po = tp;
  }

  // chol+subst (wave0) || v = E^T mu (tids 64..95) || ME = M*E (tids 256..511)
  if (tid < 64) {
    const int ci = tid & 31;
    float acc[KD];
    #pragma unroll
    for (int r = 0; r < KD; ++r) acc[r] = pe[r*LS + ci];   // E column ci
    float row[KD];
    #pragma unroll
    for (int q4 = 0; q4 < KD; q4 += 4) {
      const float4 m4 = *(const float4*)&buf[O_M + ci*LS + q4];
      row[q4] = m4.x; row[q4+1] = m4.y; row[q4+2] = m4.z; row[q4+3] = m4.w;
    }
    float Lr[KD], dinv[KD];
    float dprod = 1.f;
    #pragma unroll
    for (int j = 0; j < KD; ++j) {
      const float djj = rdlane(row[j], j);
      const float d = sqrtf(djj);
      const float rin = 1.f / d;
      dprod *= d;
      dinv[j] = rin;
      const float lij = row[j] * rin;       // valid for lanes ci >= j
      Lr[j] = lij;
      #pragma unroll
      for (int q = j + 1; q < KD; ++q)
        row[q] = fmaf(-lij, rdlane(lij, q), row[q]);
    }
    if (tid == 0) {
      const float ld = 2.f * logf(dprod);
      g_ld[g] = ld;
      buf[O_LD] = ld;
    }
    #pragma unroll
    for (int q = 0; q < KD; ++q) {          // W[:,ci] = L^-1 E[:,ci]
      const float wq = acc[q] * dinv[q];
      acc[q] = wq;
      #pragma unroll
      for (int r = q + 1; r < KD; ++r)
        acc[r] = fmaf(-rdlane(Lr[q], r), wq, acc[r]);
    }
    #pragma unroll
    for (int r = 0; r < KD; ++r) buf[O_W + r*LS + ci] = acc[r];
  } else if (tid < 96) {
    const int c = tid - 64;
    float va = 0.f;
    #pragma unroll
    for (int r = 0; r < KD; ++r) va += pe[r*LS + c] * buf[O_MU + r];
    g_v[g*KD + c] = va;
    buf[O_VV + c] = va;
  } else if (tid >= 256) {
    const int t4 = (tid - 256) * 4;         // ME = M*E -> O_B
    const int rm = t4 >> 5, cm = t4 & 31;
    float a[4] = {0.f,0.f,0.f,0.f};
    #pragma unroll
    for (int q4 = 0; q4 < KD; q4 += 4) {
      const float4 a4 = *(const float4*)&buf[O_M + rm*LS + q4];
      const float ar[4] = {a4.x, a4.y, a4.z, a4.w};
      #pragma unroll
      for (int u = 0; u < 4; ++u) {
        const float4 b4 = *(const float4*)&pe[(q4+u)*LS + cm];
        a[0] += ar[u]*b4.x; a[1] += ar[u]*b4.y;
        a[2] += ar[u]*b4.z; a[3] += ar[u]*b4.w;
      }
    }
    #pragma unroll
    for (int m = 0; m < 4; ++m) buf[O_B + rm*LS + cm + m] = a[m];
  }
  __syncthreads();

  // Q = W^T W -> global (+u partials); T' = E^T (ME) + v v^T -> global; E -> global
  {
    float aq[2] = {0.f,0.f}, at[2] = {0.f,0.f};
    #pragma unroll
    for (int q = 0; q < KD; ++q) {
      const float wq = buf[O_W + q*LS + r0];
      const float eq = pe[q*LS + r0];
      const float2 wb = *(const float2*)&buf[O_W + q*LS + c0];
      const float2 mb = *(const float2*)&buf[O_B + q*LS + c0];
      aq[0] += wq*wb.x; aq[1] += wq*wb.y;
      at[0] += eq*mb.x; at[1] += eq*mb.y;
    }
    const float vr = buf[O_VV + r0];
    const float vc0 = buf[O_VV + c0], vc1 = buf[O_VV + c0 + 1];
    at[0] += vr * vc0;
    at[1] += vr * vc1;
    *(float2*)&g_Q[(size_t)g*1024 + r0*KD + c0] = make_float2(aq[0], aq[1]);
    *(float2*)&g_T[(size_t)g*1024 + r0*KD + c0] = make_float2(at[0], at[1]);
    *(float2*)&g_E[(size_t)g*1024 + r0*KD + c0] =
        make_float2(pe[r0*LS + c0], pe[r0*LS + c0 + 1]);
    // u partial: this thread's Q elems dotted with v
    buf[O_P + r0*16 + (c0 >> 1)] = aq[0]*vc0 + aq[1]*vc1;
  }
  __syncthreads();

  if (tid < KD) {
    float u = 0.f;
    #pragma unroll
    for (int m = 0; m < 16; ++m) u += buf[O_P + tid*16 + m];
    g_u[g*KD + tid] = u;
    float t = u * buf[O_VV + tid];           // partial of v^T Q v
    #pragma unroll
    for (int o = 1; o < 32; o <<= 1) t += __shfl_xor(t, o);
    if (tid == 0) g_c[g] = 0.5f*(t + buf[O_LD] - (float)KD);
  }
}

// ---------------- Kernel 2: pairwise KL + softmax + aggregate ----------------
__global__ __launch_bounds__(512, 1) void pair_kernel(float* __restrict__ out) {
  const int g = blockIdx.x;
  const int b = g >> 7;
  const int i = g & (NA - 1);
  const int tid = threadIdx.x;
  __shared__ __align__(16) float sv[NA*KD];   // 16 KB
  __shared__ __align__(16) float su[NA*KD];   // 16 KB
  __shared__ float sc[NA];
  __shared__ float skl[NA];
  __shared__ float sbe[NA];
  __shared__ float sp[16*KD];
  __shared__ float sw[KD];

  {
    const float4* vs = (const float4*)(g_v + (size_t)b*NA*KD);
    const float4* us = (const float4*)(g_u + (size_t)b*NA*KD);
    float4* dv = (float4*)sv;
    float4* du = (float4*)su;
    dv[tid]       = vs[tid];
    dv[tid + 512] = vs[tid + 512];
    du[tid]       = us[tid];
    du[tid + 512] = us[tid + 512];
    if (tid < NA) sc[tid] = g_c[b*NA + tid];
  }

  const int lane = tid & 63;
  const int wave = tid >> 6;
  const int k  = lane >> 1;
  const int l0 = (lane & 1) * 16;
  const bool even = (lane & 1) == 0;

  // T'_i row chunk in registers (lane-constant over the whole j loop)
  float4 t0, t1, t2, t3;
  {
    const float4* Tp = (const float4*)(g_T + (size_t)g*1024 + k*KD + l0);
    t0 = Tp[0]; t1 = Tp[1]; t2 = Tp[2]; t3 = Tp[3];
  }
  const float ldi = g_ld[g];
  __syncthreads();

  const float vik = sv[i*KD + k];
  const float* Qb = g_Q + (size_t)b*NA*1024 + k*KD + l0;

  #pragma unroll 2
  for (int j = wave; j < NA; j += 8) {
    const float4* Qp = (const float4*)(Qb + (size_t)j*1024);
    const float4 q0 = Qp[0], q1 = Qp[1], q2 = Qp[2], q3 = Qp[3];
    float part = 0.5f*(d4(q0,t0) + d4(q1,t1) + d4(q2,t2) + d4(q3,t3));
    if (even) part = fmaf(-su[j*KD + k], vik, part);
    #pragma unroll
    for (int o = 1; o < 64; o <<= 1) part += __shfl_xor(part, o);
    if (lane == 0)
      skl[j] = fmaxf(part + sc[j] - 0.5f*ldi, 0.f);
  }
  __syncthreads();

  // softmax over j in one wave: lane holds kl[lane], kl[lane+64]
  if (tid < 64) {
    const float a = skl[tid], c = skl[tid + 64];
    float mn = fminf(a, c);
    #pragma unroll
    for (int o = 1; o < 64; o <<= 1) mn = fminf(mn, __shfl_xor(mn, o));
    const float ea = expf(mn - a);
    const float eb = expf(mn - c);
    float sm = ea + eb;
    #pragma unroll
    for (int o = 1; o < 64; o <<= 1) sm += __shfl_xor(sm, o);
    const float inv = 1.f / sm;
    const float ren = 1.0f / (1.0f + 128.0f * 1e-8f);
    sbe[tid]      = (ea*inv + 1e-8f) * ren;
    sbe[tid + 64] = (eb*inv + 1e-8f) * ren;
  }
  __syncthreads();

  // w = sum_j beta_j v_j (16 chunks x 32 components)
  {
    const int c = tid >> 5, kk = tid & 31;
    float acc = 0.f;
    #pragma unroll
    for (int jj = 0; jj < 8; ++jj) {
      const int j = c*8 + jj;
      acc += sbe[j] * sv[j*KD + kk];
    }
    sp[c*KD + kk] = acc;
  }
  __syncthreads();
  if (tid < KD) {
    float w = 0.f;
    #pragma unroll
    for (int c2 = 0; c2 < 16; ++c2) w += sp[c2*KD + tid];
    sw[tid] = w;
  }
  __syncthreads();
  if (tid < KD) {
    const float* Ei = g_E + (size_t)g*1024 + tid*KD;
    float acc = 0.f;
    #pragma unroll
    for (int l = 0; l < KD; ++l) acc += Ei[l] * sw[l];
    out[g*KD + tid] = acc;
  }
}

extern "C" void kernel_launch(void* const* d_in, const int* in_sizes, int n_in,
                              void* d_out, int out_size, void* d_ws, size_t ws_size,
                              hipStream_t stream) {
  (void)in_sizes; (void)n_in; (void)out_size; (void)d_ws; (void)ws_size;
  const float* mu_q    = (const float*)d_in[0];
  const float* sigma_q = (const float*)d_in[1];
  const float* phi     = (const float*)d_in[2];
  const float* gen     = (const float*)d_in[3];
  float* out = (float*)d_out;
  hipLaunchKernelGGL(agent_kernel, dim3(BN), dim3(512), 0, stream,
                     mu_q, sigma_q, phi, gen);
  hipLaunchKernelGGL(pair_kernel, dim3(BN), dim3(512), 0, stream, out);
}

// Round 7
// 90.851 us; speedup vs baseline: 1.4807x; 1.0066x over previous
//
#include <hip/hip_runtime.h>
#include <math.h>

#define NB 2
#define NA 128
#define KD 32
#define LS 36            // LDS row stride: conflict-free for row/col float4 access
#define BN (NB*NA)       // 256 agents total
#define EPSV 1e-8f

// Inter-kernel scratch (graph-capture-safe; fully rewritten every launch).
__device__ __align__(16) float g_Q[BN*KD*KD];   // E^T (Sig+eps)^-1 E
__device__ __align__(16) float g_T[BN*KD*KD];   // T' = E^T (Sig+eps) E + v v^T
__device__ __align__(16) float g_E[BN*KD*KD];   // expm(X)
__device__ __align__(16) float g_v[BN*KD];      // v = E^T mu
__device__ __align__(16) float g_u[BN*KD];      // u = Q v
__device__ __align__(16) float g_ld[BN];        // logdet(Sig+eps)
__device__ __align__(16) float g_c[BN];         // 0.5*(v^T Q v + ld - K)

// agent-phase LDS float offsets
#define O_M   0
#define O_X   1152      // unscaled X; dead after P3 -> reused as L (chol)
#define O_X2  2304      // unscaled X^2
#define O_X4  3456      // scaled X^4
#define O_B   4608      // B-poly, later ME = M*E
#define O_W   5760      // W = L^-1 E
#define O_E   6912
#define O_F   8064      // squaring ping-pong
#define O_VV  9216      // 32: v
#define O_DG  9248      // 8: per-wave norm partials
#define O_P   9280      // 512: u partial sums [32 rows][16]
#define O_MU  9792      // 32
#define O_LD  9824      // 1
#define O_TOT 9828      // ~39.3 KB
#define O_L   O_X       // L factor region (X dead by chol time)

__device__ __forceinline__ float rdlane(float x, int l) {
  return __int_as_float(__builtin_amdgcn_readlane(__float_as_int(x), l));
}
__device__ __forceinline__ float d4(float4 a, float4 b) {
  return a.x*b.x + a.y*b.y + a.z*b.z + a.w*b.w;
}

// acc[m] += sum_q A[r0][q] * B[q][c0+m], 2 outputs (LS-strided LDS tiles)
__device__ __forceinline__ void mm2(const float* A, const float* B,
                                    int r0, int c0, float acc[2]) {
  #pragma unroll
  for (int q4 = 0; q4 < KD; q4 += 4) {
    const float4 a4 = *(const float4*)&A[r0*LS + q4];
    const float ar[4] = {a4.x, a4.y, a4.z, a4.w};
    #pragma unroll
    for (int u = 0; u < 4; ++u) {
      const float2 b2 = *(const float2*)&B[(q4+u)*LS + c0];
      acc[0] += ar[u]*b2.x; acc[1] += ar[u]*b2.y;
    }
  }
}

// ---- Cholesky via template recursion: ALL array indices compile-time ----
// (rule #20: runtime-indexed per-lane arrays lower to scratch; the 32-iter
// loop is too big for the compiler's unroller, so force it structurally.)
template<int J> struct Chol {
  static __device__ __forceinline__ void run(float (&row)[KD], float (&dinv)[KD],
                                             float& dprod, float* sL, int ci) {
    const float djj = rdlane(row[J], J);
    const float d = sqrtf(djj);
    const float rin = 1.f / d;
    dprod *= d;
    dinv[J] = rin;
    const float lij = row[J] * rin;       // valid for lanes ci >= J
    sL[ci*LS + J] = lij;
    #pragma unroll
    for (int q = J + 1; q < KD; ++q)
      row[q] = fmaf(-lij, rdlane(lij, q), row[q]);
    Chol<J+1>::run(row, dinv, dprod, sL, ci);
  }
};
template<> struct Chol<KD> {
  static __device__ __forceinline__ void run(float (&)[KD], float (&)[KD],
                                             float&, float*, int) {}
};

template<int Q> struct Subst {
  static __device__ __forceinline__ void run(float (&acc)[KD],
                                             const float (&dinv)[KD],
                                             const float* sL) {
    const float wq = acc[Q] * dinv[Q];
    acc[Q] = wq;
    #pragma unroll
    for (int r = Q + 1; r < KD; ++r)
      acc[r] = fmaf(-sL[r*LS + Q], wq, acc[r]);   // same-addr broadcast reads
    Subst<Q+1>::run(acc, dinv, sL);
  }
};
template<> struct Subst<KD> {
  static __device__ __forceinline__ void run(float (&)[KD], const float (&)[KD],
                                             const float*) {}
};

// ---------------- Kernel 1: per-agent factorizations ----------------
__global__ __launch_bounds__(512, 1) void agent_kernel(
    const float* __restrict__ mu_q, const float* __restrict__ sigma_q,
    const float* __restrict__ phi, const float* __restrict__ gen) {
  __shared__ __align__(16) float buf[O_TOT];
  const int g = blockIdx.x;
  const int tid = threadIdx.x;
  const int e0 = tid * 2;
  const int r0 = e0 >> 5;
  const int c0 = e0 & 31;          // 2 consecutive cols (c0 even)

  const float p0 = phi[g*3+0], p1 = phi[g*3+1], p2 = phi[g*3+2];
  if (tid < KD) buf[O_MU + tid] = mu_q[g*KD + tid];
  float x0, x1;
  {
    const float2 sg = *(const float2*)(sigma_q + (size_t)g*1024 + e0);
    const float2 g0 = *(const float2*)(gen + e0);
    const float2 g1 = *(const float2*)(gen + 1024 + e0);
    const float2 g2 = *(const float2*)(gen + 2048 + e0);
    x0 = p0*g0.x + p1*g1.x + p2*g2.x;
    x1 = p0*g0.y + p1*g1.y + p2*g2.y;
    buf[O_X + r0*LS + c0]     = x0;
    buf[O_X + r0*LS + c0 + 1] = x1;
    buf[O_M + r0*LS + c0]     = sg.x + ((r0 == c0)     ? EPSV : 0.f);
    buf[O_M + r0*LS + c0 + 1] = sg.y + ((r0 == c0 + 1) ? EPSV : 0.f);
  }
  // per-wave Frobenius-norm partials (no atomic, no extra barrier)
  {
    float nrm = x0*x0 + x1*x1;
    #pragma unroll
    for (int o = 1; o < 64; o <<= 1) nrm += __shfl_xor(nrm, o);
    if ((tid & 63) == 0) buf[O_DG + (tid >> 6)] = nrm;
  }
  __syncthreads();

  float snrm = 0.f;
  #pragma unroll
  for (int w = 0; w < 8; ++w) snrm += buf[O_DG + w];
  const float anorm = sqrtf(snrm);
  int s = 0;
  if (anorm > 1.f) { s = (int)ceilf(log2f(anorm)); s = min(s, 15); }
  const float sc1 = exp2f((float)(-s));
  const float sc2 = sc1*sc1, sc3 = sc2*sc1, sc4 = sc2*sc2;

  // P1: X2u = Xu*Xu (unscaled)
  {
    float a2[2] = {0.f, 0.f};
    mm2(buf + O_X, buf + O_X, r0, c0, a2);
    buf[O_X2 + r0*LS + c0]     = a2[0];
    buf[O_X2 + r0*LS + c0 + 1] = a2[1];
  }
  __syncthreads();

  // P2: X3u = X2u*Xu, X4u = X2u*X2u; scale-fold; B = c4 I + c5 Xs + c6 X2s + c7 X3s
  const float C4 = 1.f/24.f, C5 = 1.f/120.f, C6 = 1.f/720.f, C7 = 1.f/5040.f;
  float x3v0, x3v1;
  const float dlt0 = (r0 == c0) ? 1.f : 0.f, dlt1 = (r0 == c0+1) ? 1.f : 0.f;
  {
    float a3[2] = {0.f,0.f}, a4[2] = {0.f,0.f};
    mm2(buf + O_X2, buf + O_X,  r0, c0, a3);
    mm2(buf + O_X2, buf + O_X2, r0, c0, a4);
    const float xs0 = buf[O_X + r0*LS + c0]*sc1, xs1 = buf[O_X + r0*LS + c0+1]*sc1;
    const float x2s0 = buf[O_X2 + r0*LS + c0]*sc2, x2s1 = buf[O_X2 + r0*LS + c0+1]*sc2;
    x3v0 = a3[0]*sc3; x3v1 = a3[1]*sc3;
    buf[O_X4 + r0*LS + c0]     = a4[0]*sc4;
    buf[O_X4 + r0*LS + c0 + 1] = a4[1]*sc4;
    buf[O_B + r0*LS + c0]      = C4*dlt0 + C5*xs0 + C6*x2s0 + C7*x3v0;
    buf[O_B + r0*LS + c0 + 1]  = C4*dlt1 + C5*xs1 + C6*x2s1 + C7*x3v1;
  }
  __syncthreads();

  // P3: E = (I + Xs + X2s/2 + X3s/6) + B*X4s
  {
    float u[2] = {0.f, 0.f};
    mm2(buf + O_B, buf + O_X4, r0, c0, u);
    const float xs0 = buf[O_X + r0*LS + c0]*sc1, xs1 = buf[O_X + r0*LS + c0+1]*sc1;
    const float x2s0 = buf[O_X2 + r0*LS + c0]*sc2, x2s1 = buf[O_X2 + r0*LS + c0+1]*sc2;
    buf[O_E + r0*LS + c0]     = dlt0 + xs0 + 0.5f*x2s0 + (1.f/6.f)*x3v0 + u[0];
    buf[O_E + r0*LS + c0 + 1] = dlt1 + xs1 + 0.5f*x2s1 + (1.f/6.f)*x3v1 + u[1];
  }
  __syncthreads();

  // squarings: E <- E*E, s times
  float* pe = buf + O_E;
  float* po = buf + O_F;
  for (int t = 0; t < s; ++t) {
    float ac[2] = {0.f, 0.f};
    mm2(pe, pe, r0, c0, ac);
    po[r0*LS + c0]     = ac[0];
    po[r0*LS + c0 + 1] = ac[1];
    __syncthreads();
    float* tp = pe; pe = po; po = tp;
  }

  // chol+subst (lanes 0..31) || v = E^T mu (tids 64..95) || ME = M*E (tids 256..511)
  if (tid < 32) {
    const int ci = tid;
    float row[KD];
    #pragma unroll
    for (int q4 = 0; q4 < KD; q4 += 4) {
      const float4 m4 = *(const float4*)&buf[O_M + ci*LS + q4];
      row[q4] = m4.x; row[q4+1] = m4.y; row[q4+2] = m4.z; row[q4+3] = m4.w;
    }
    float dinv[KD];
    float dprod = 1.f;
    Chol<0>::run(row, dinv, dprod, buf + O_L, ci);
    if (tid == 0) {
      const float ld = 2.f * logf(dprod);
      g_ld[g] = ld;
      buf[O_LD] = ld;
    }
    // load E column AFTER chol so row/acc live ranges don't overlap
    float acc[KD];
    #pragma unroll
    for (int r = 0; r < KD; ++r) acc[r] = pe[r*LS + ci];
    Subst<0>::run(acc, dinv, buf + O_L);
    #pragma unroll
    for (int r = 0; r < KD; ++r) buf[O_W + r*LS + ci] = acc[r];
  } else if (tid >= 64 && tid < 96) {
    const int c = tid - 64;
    float va = 0.f;
    #pragma unroll
    for (int r = 0; r < KD; ++r) va += pe[r*LS + c] * buf[O_MU + r];
    g_v[g*KD + c] = va;
    buf[O_VV + c] = va;
  } else if (tid >= 256) {
    const int t4 = (tid - 256) * 4;         // ME = M*E -> O_B
    const int rm = t4 >> 5, cm = t4 & 31;
    float a[4] = {0.f,0.f,0.f,0.f};
    #pragma unroll
    for (int q4 = 0; q4 < KD; q4 += 4) {
      const float4 a4 = *(const float4*)&buf[O_M + rm*LS + q4];
      const float ar[4] = {a4.x, a4.y, a4.z, a4.w};
      #pragma unroll
      for (int u = 0; u < 4; ++u) {
        const float4 b4 = *(const float4*)&pe[(q4+u)*LS + cm];
        a[0] += ar[u]*b4.x; a[1] += ar[u]*b4.y;
        a[2] += ar[u]*b4.z; a[3] += ar[u]*b4.w;
      }
    }
    #pragma unroll
    for (int m = 0; m < 4; ++m) buf[O_B + rm*LS + cm + m] = a[m];
  }
  __syncthreads();

  // Q = W^T W -> global (+u partials); T' = E^T (ME) + v v^T -> global; E -> global
  {
    float aq[2] = {0.f,0.f}, at[2] = {0.f,0.f};
    #pragma unroll
    for (int q = 0; q < KD; ++q) {
      const float wq = buf[O_W + q*LS + r0];
      const float eq = pe[q*LS + r0];
      const float2 wb = *(const float2*)&buf[O_W + q*LS + c0];
      const float2 mb = *(const float2*)&buf[O_B + q*LS + c0];
      aq[0] += wq*wb.x; aq[1] += wq*wb.y;
      at[0] += eq*mb.x; at[1] += eq*mb.y;
    }
    const float vr = buf[O_VV + r0];
    const float vc0 = buf[O_VV + c0], vc1 = buf[O_VV + c0 + 1];
    at[0] += vr * vc0;
    at[1] += vr * vc1;
    *(float2*)&g_Q[(size_t)g*1024 + r0*KD + c0] = make_float2(aq[0], aq[1]);
    *(float2*)&g_T[(size_t)g*1024 + r0*KD + c0] = make_float2(at[0], at[1]);
    *(float2*)&g_E[(size_t)g*1024 + r0*KD + c0] =
        make_float2(pe[r0*LS + c0], pe[r0*LS + c0 + 1]);
    // u partial: this thread's Q elems dotted with v
    buf[O_P + r0*16 + (c0 >> 1)] = aq[0]*vc0 + aq[1]*vc1;
  }
  __syncthreads();

  if (tid < KD) {
    float u = 0.f;
    #pragma unroll
    for (int m = 0; m < 16; ++m) u += buf[O_P + tid*16 + m];
    g_u[g*KD + tid] = u;
    float t = u * buf[O_VV + tid];           // partial of v^T Q v
    #pragma unroll
    for (int o = 1; o < 32; o <<= 1) t += __shfl_xor(t, o);
    if (tid == 0) g_c[g] = 0.5f*(t + buf[O_LD] - (float)KD);
  }
}

// ---------------- Kernel 2: pairwise KL + softmax + aggregate ----------------
__global__ __launch_bounds__(512, 1) void pair_kernel(float* __restrict__ out) {
  const int g = blockIdx.x;
  const int b = g >> 7;
  const int i = g & (NA - 1);
  const int tid = threadIdx.x;
  __shared__ __align__(16) float sv[NA*KD];   // 16 KB
  __shared__ __align__(16) float su[NA*KD];   // 16 KB
  __shared__ float sc[NA];
  __shared__ float skl[NA];
  __shared__ float sbe[NA];
  __shared__ float sp[16*KD];
  __shared__ float sw[KD];

  {
    const float4* vs = (const float4*)(g_v + (size_t)b*NA*KD);
    const float4* us = (const float4*)(g_u + (size_t)b*NA*KD);
    float4* dv = (float4*)sv;
    float4* du = (float4*)su;
    dv[tid]       = vs[tid];
    dv[tid + 512] = vs[tid + 512];
    du[tid]       = us[tid];
    du[tid + 512] = us[tid + 512];
    if (tid < NA) sc[tid] = g_c[b*NA + tid];
  }

  const int lane = tid & 63;
  const int wave = tid >> 6;
  const int k  = lane >> 1;
  const int l0 = (lane & 1) * 16;
  const bool even = (lane & 1) == 0;

  // T'_i row chunk in registers (lane-constant over the whole j loop)
  float4 t0, t1, t2, t3;
  {
    const float4* Tp = (const float4*)(g_T + (size_t)g*1024 + k*KD + l0);
    t0 = Tp[0]; t1 = Tp[1]; t2 = Tp[2]; t3 = Tp[3];
  }
  const float ldi = g_ld[g];
  __syncthreads();

  const float vik = sv[i*KD + k];
  const float* Qb = g_Q + (size_t)b*NA*1024 + k*KD + l0;

  #pragma unroll 2
  for (int j = wave; j < NA; j += 8) {
    const float4* Qp = (const float4*)(Qb + (size_t)j*1024);
    const float4 q0 = Qp[0], q1 = Qp[1], q2 = Qp[2], q3 = Qp[3];
    float part = 0.5f*(d4(q0,t0) + d4(q1,t1) + d4(q2,t2) + d4(q3,t3));
    if (even) part = fmaf(-su[j*KD + k], vik, part);
    #pragma unroll
    for (int o = 1; o < 64; o <<= 1) part += __shfl_xor(part, o);
    if (lane == 0)
      skl[j] = fmaxf(part + sc[j] - 0.5f*ldi, 0.f);
  }
  __syncthreads();

  // softmax over j in one wave: lane holds kl[lane], kl[lane+64]
  if (tid < 64) {
    const float a = skl[tid], c = skl[tid + 64];
    float mn = fminf(a, c);
    #pragma unroll
    for (int o = 1; o < 64; o <<= 1) mn = fminf(mn, __shfl_xor(mn, o));
    const float ea = expf(mn - a);
    const float eb = expf(mn - c);
    float sm = ea + eb;
    #pragma unroll
    for (int o = 1; o < 64; o <<= 1) sm += __shfl_xor(sm, o);
    const float inv = 1.f / sm;
    const float ren = 1.0f / (1.0f + 128.0f * 1e-8f);
    sbe[tid]      = (ea*inv + 1e-8f) * ren;
    sbe[tid + 64] = (eb*inv + 1e-8f) * ren;
  }
  __syncthreads();

  // w = sum_j beta_j v_j (16 chunks x 32 components)
  {
    const int c = tid >> 5, kk = tid & 31;
    float acc = 0.f;
    #pragma unroll
    for (int jj = 0; jj < 8; ++jj) {
      const int j = c*8 + jj;
      acc += sbe[j] * sv[j*KD + kk];
    }
    sp[c*KD + kk] = acc;
  }
  __syncthreads();
  if (tid < KD) {
    float w = 0.f;
    #pragma unroll
    for (int c2 = 0; c2 < 16; ++c2) w += sp[c2*KD + tid];
    sw[tid] = w;
  }
  __syncthreads();
  if (tid < KD) {
    const float* Ei = g_E + (size_t)g*1024 + tid*KD;
    float acc = 0.f;
    #pragma unroll
    for (int l = 0; l < KD; ++l) acc += Ei[l] * sw[l];
    out[g*KD + tid] = acc;
  }
}

extern "C" void kernel_launch(void* const* d_in, const int* in_sizes, int n_in,
                              void* d_out, int out_size, void* d_ws, size_t ws_size,
                              hipStream_t stream) {
  (void)in_sizes; (void)n_in; (void)out_size; (void)d_ws; (void)ws_size;
  const float* mu_q    = (const float*)d_in[0];
  const float* sigma_q = (const float*)d_in[1];
  const float* phi     = (const float*)d_in[2];
  const float* gen     = (const float*)d_in[3];
  float* out = (float*)d_out;
  hipLaunchKernelGGL(agent_kernel, dim3(BN), dim3(512), 0, stream,
                     mu_q, sigma_q, phi, gen);
  hipLaunchKernelGGL(pair_kernel, dim3(BN), dim3(512), 0, stream, out);
}